// Round 10
// baseline (54.302 us; speedup 1.0000x reference)
//
#include <hip/hip_runtime.h>
#include <hip/hip_bf16.h>

#define NB 4
#define NH 16
#define SEQ 2048
#define EMB 512
#define DH 32
#define CHUNKQ 64
#define WIN 256

typedef __attribute__((ext_vector_type(8))) short short8;
typedef __attribute__((ext_vector_type(4))) float f32x4;

// packed f32x2 -> bf16x2 (RNE); HW-validated rounds 3/6/8
__device__ __forceinline__ unsigned cvt_pk_bf16(float lo, float hi) {
    unsigned r;
    asm("v_cvt_pk_bf16_f32 %0, %1, %2" : "=v"(r) : "v"(lo), "v"(hi));
    return r;
}

// === r8 (green, 26.4us) + ONE delta: drop Ks, K A-frags direct from global ===
// K's A-fragment is 8 CONTIGUOUS dims (32B) per lane -> load from global with
// a 1-deep software prefetch inside the t-loop (latency hides under each
// iteration's MFMA+exp+Pbuf chain); conversion uses the same cvt_pk RNE as
// the old staging, so values are bit-identical. V stays in LDS (its fragment
// would be a stride-2KB 2-byte gather from global). Pbuf transit unchanged.
//
// LDS: Vt [32][328] bf16 (20992 B) + Pbuf 4 x [16][20] u32 (5120 B)
//    = 26112 B; with __launch_bounds__(256,4) (VGPR<=128) -> 4 blocks/CU
//    (16 waves/CU, +33% TLP vs r8's 3 blocks). K re-read 4x/block is
//    L1/L2-absorbed (same 128B rows touched by all 4 waves).

__global__ __launch_bounds__(256, 4)
void attn_chunk_kernel(const float* __restrict__ q, const float* __restrict__ k,
                       const float* __restrict__ v, float* __restrict__ out)
{
    constexpr int VSTR = 328;   // Vt row stride (bf16)
    constexpr int PSTR = 20;    // Pbuf row stride (u32)
    __shared__ __align__(16) ushort Vt[32 * VSTR];
    __shared__ __align__(16) unsigned Pbuf[4][16 * PSTR];

    // XCD-aware swizzle: 2048 blocks, 8 XCDs -> contiguous 256-block chunk/XCD
    const unsigned bid = (blockIdx.x & 7) * 256 + (blockIdx.x >> 3);
    const int cid = bid & 31;          // chunk id
    const int h   = (bid >> 5) & 15;   // head
    const int b   = bid >> 9;          // batch
    const int q0  = cid * CHUNKQ;
    const int hi  = q0 + CHUNKQ;
    const int kstart = (hi - 320 > 0) ? (hi - 320) : 0;
    const int KT  = hi - kstart;       // 64..320, multiple of 64

    const int tid = threadIdx.x;
    const int d2  = (tid & 15) * 2;    // V-staging dim pair 0,2,..,30
    const int kp  = tid >> 4;          // V-staging key-pair 0..15

    // ---- V staging loads: ALL issued first, unconditional (always in-bounds:
    //      kstart + row <= hi-1 <= 2047; extra cols written but never read) ----
    float2 va[10], vb[10];
    #pragma unroll
    for (int it = 0; it < 10; ++it) {
        const size_t vbase = (size_t)(b * SEQ + kstart + 32 * it + 2 * kp) * EMB + h * DH + d2;
        va[it] = *(const float2*)(v + vbase);          // key 32it+2kp, dims d2,d2+1
        vb[it] = *(const float2*)(v + vbase + EMB);    // key 32it+2kp+1
    }

    const int w   = tid >> 6;          // wave 0..3 owns queries [16w, 16w+16)
    const int l   = tid & 63;
    const int l16 = l & 15;
    const int kg  = l >> 4;            // 0..3
    const int k0  = kg * 8;            // dim slice for frags

    // ---- Q B-frag direct from global (overlaps the staging-load latency) ----
    const float* qrow = q + ((size_t)(b * SEQ + q0 + 16 * w + l16) * EMB + h * DH + k0);
    const float4 qa = *(const float4*)qrow;
    const float4 qc = *(const float4*)(qrow + 4);
    union { short8 s; unsigned u[4]; } qb;
    qb.u[0] = cvt_pk_bf16(qa.x, qa.y);
    qb.u[1] = cvt_pk_bf16(qa.z, qa.w);
    qb.u[2] = cvt_pk_bf16(qc.x, qc.y);
    qb.u[3] = cvt_pk_bf16(qc.z, qc.w);

    // ---- V converts + LDS writes (unconditional; b32 key-pair packed) ----
    #pragma unroll
    for (int it = 0; it < 10; ++it) {
        *(unsigned*)(Vt + (d2 + 0) * VSTR + 32 * it + 2 * kp) = cvt_pk_bf16(va[it].x, vb[it].x);
        *(unsigned*)(Vt + (d2 + 1) * VSTR + 32 * it + 2 * kp) = cvt_pk_bf16(va[it].y, vb[it].y);
    }

    // ---- K fragment pointers + t=0 prefetch (issued BEFORE the barrier so
    //      the load latency hides under the barrier wait) ----
    const float* kbase_lo = k + ((size_t)(b * SEQ + kstart + l16) * EMB + h * DH + k0);
    const float* kbase_hi = kbase_lo + (size_t)16 * EMB;
    float4 ka0 = *(const float4*)(kbase_lo);
    float4 ka1 = *(const float4*)(kbase_lo + 4);
    float4 kb0 = *(const float4*)(kbase_hi);
    float4 kb1 = *(const float4*)(kbase_hi + 4);

    __syncthreads();   // the only barrier

    const float scale = 0.17677669529663687f;  // 1/sqrt(32)
    const int   iq    = q0 + 16 * w + l16;     // this lane's query (key-major domain)
    const int   lowk  = iq - (WIN - 1);        // allowed keys: [lowk, hi)
    unsigned* pw = &Pbuf[w][l16 * PSTR];

    const f32x4 zero = {0.f, 0.f, 0.f, 0.f};
    f32x4 o0 = zero, o1 = zero;
    float srow = 0.f;

    #pragma unroll
    for (int t = 0; t < 10; ++t) {
        if (t * 32 < KT) {
            // convert the in-flight K registers to bf16 frags (same idiom as qb)
            union { short8 s; unsigned u[4]; } kaf, kbf;
            kaf.u[0] = cvt_pk_bf16(ka0.x, ka0.y);
            kaf.u[1] = cvt_pk_bf16(ka0.z, ka0.w);
            kaf.u[2] = cvt_pk_bf16(ka1.x, ka1.y);
            kaf.u[3] = cvt_pk_bf16(ka1.z, ka1.w);
            kbf.u[0] = cvt_pk_bf16(kb0.x, kb0.y);
            kbf.u[1] = cvt_pk_bf16(kb0.z, kb0.w);
            kbf.u[2] = cvt_pk_bf16(kb1.x, kb1.y);
            kbf.u[3] = cvt_pk_bf16(kb1.z, kb1.w);

            // prefetch K for t+1 (rows kstart+32(t+1)+l16 <= kstart+319 in-bounds)
            if (t < 9) {
                const float* pl = kbase_lo + (size_t)(t + 1) * 32 * EMB;
                const float* ph = kbase_hi + (size_t)(t + 1) * 32 * EMB;
                ka0 = *(const float4*)(pl);
                ka1 = *(const float4*)(pl + 4);
                kb0 = *(const float4*)(ph);
                kb1 = *(const float4*)(ph + 4);
            }

            // QK^T (swapped): A = K rows, B = Q. D[key=4kg+r][q=l16]
            f32x4 s_lo = __builtin_amdgcn_mfma_f32_16x16x32_bf16(kaf.s, qb.s, zero, 0, 0, 0);
            f32x4 s_hi = __builtin_amdgcn_mfma_f32_16x16x32_bf16(kbf.s, qb.s, zero, 0, 0, 0);

            // mask + exp (no max-sub: scores bounded, fp32-safe); sum in-lane
            const int kk = kstart + 32 * t + 4 * kg;
            float p[8];
            #pragma unroll
            for (int r = 0; r < 4; ++r) {
                p[r]     = (kk + r      >= lowk) ? __expf(s_lo[r] * scale) : 0.f;
                p[r + 4] = (kk + r + 16 >= lowk) ? __expf(s_hi[r] * scale) : 0.f;
            }
            srow += ((p[0] + p[1]) + (p[2] + p[3])) + ((p[4] + p[5]) + (p[6] + p[7]));

            // pack & transit through wave-private Pbuf to A-frag layout
            uint2 wlo, whi;
            wlo.x = cvt_pk_bf16(p[0], p[1]);  wlo.y = cvt_pk_bf16(p[2], p[3]);
            whi.x = cvt_pk_bf16(p[4], p[5]);  whi.y = cvt_pk_bf16(p[6], p[7]);
            *(uint2*)(pw + 2 * kg)     = wlo;   // keys 4kg..4kg+3
            *(uint2*)(pw + 8 + 2 * kg) = whi;   // keys 16+4kg..+3
            const short8 pa = *(const short8*)(pw + 4 * kg);  // P[q=l16][keys 8kg..8kg+7]

            // PV: B = Vt rows (dims), accumulate
            const short8 bv0 = *(const short8*)(Vt + l16 * VSTR + 32 * t + k0);
            const short8 bv1 = *(const short8*)(Vt + (16 + l16) * VSTR + 32 * t + k0);
            o0 = __builtin_amdgcn_mfma_f32_16x16x32_bf16(pa, bv0, o0, 0, 0, 0);
            o1 = __builtin_amdgcn_mfma_f32_16x16x32_bf16(pa, bv1, o1, 0, 0, 0);
        }
    }

    // ---- epilogue: reduce row-sum (keys partitioned over kg/halves), write ----
    srow += __shfl_xor(srow, 16);
    srow += __shfl_xor(srow, 32);   // srow(q=l16) valid in all kg groups
    #pragma unroll
    for (int r = 0; r < 4; ++r) {
        const float sq  = __shfl(srow, 4 * kg + r);     // srow for query 4kg+r
        const float inv = 1.0f / sq;
        float* dst = out + (size_t)(b * SEQ + q0 + 16 * w + 4 * kg + r) * EMB + h * DH;
        dst[l16]      = o0[r] * inv;
        dst[16 + l16] = o1[r] * inv;
    }
}

extern "C" void kernel_launch(void* const* d_in, const int* in_sizes, int n_in,
                              void* d_out, int out_size, void* d_ws, size_t ws_size,
                              hipStream_t stream) {
    const float* q = (const float*)d_in[0];
    const float* k = (const float*)d_in[1];
    const float* v = (const float*)d_in[2];
    float* out = (float*)d_out;
    const int grid = NB * NH * (SEQ / CHUNKQ);   // 2048 blocks
    attn_chunk_kernel<<<grid, 256, 0, stream>>>(q, k, v, out);
}

// Round 11
// 27.669 us; speedup vs baseline: 1.9626x; 1.9626x over previous
//
#include <hip/hip_runtime.h>
#include <hip/hip_bf16.h>

#define NB 4
#define NH 16
#define SEQ 2048
#define EMB 512
#define DH 32
#define CHUNKQ 64
#define WIN 256

typedef __attribute__((ext_vector_type(8))) short short8;
typedef __attribute__((ext_vector_type(4))) float f32x4;

// packed f32x2 -> bf16x2 (RNE); HW-validated rounds 3/6/8
__device__ __forceinline__ unsigned cvt_pk_bf16(float lo, float hi) {
    unsigned r;
    asm("v_cvt_pk_bf16_f32 %0, %1, %2" : "=v"(r) : "v"(lo), "v"(hi));
    return r;
}

// === r8 (green, 26.4us) + ONE delta: key-parity split, 512-thr blocks ===
// 8 waves per chunk: wave = (query-block wq=w&3, phase ph=w>>2). Phase 0
// computes EVEN key-tiles, phase 1 ODD tiles (KT % 64 == 0 -> perfectly
// balanced). Per-wave t-loop: 10 -> 5 iterations (chain halved); staging
// per-thread halved. Per-tile mechanics verbatim r8 (Ks/Vt/Pbuf/mask/exp).
// Combine: phase-1 waves write partial {o0,o1,srow} to a 9.2KB buffer
// OVERLAID on Ks (dead after the loop, barrier-protected); phase-0 adds
// lane-wise and runs the r8 epilogue.
//
// LDS: Ks [320][40] (25600) + Vt [32][328] (20992) + Pbuf 8x[16][20] u32
// (10240) = 56832 B -> 2 blocks/CU = 16 waves/CU (+33% TLP vs r8).

__global__ __launch_bounds__(512, 4)
void attn_chunk_kernel(const float* __restrict__ q, const float* __restrict__ k,
                       const float* __restrict__ v, float* __restrict__ out)
{
    constexpr int KSTR = 40;    // Ks row stride (bf16)
    constexpr int VSTR = 328;   // Vt row stride (bf16)
    constexpr int PSTR = 20;    // Pbuf row stride (u32)
    __shared__ __align__(16) ushort Ks[320 * KSTR];
    __shared__ __align__(16) ushort Vt[32 * VSTR];
    __shared__ __align__(16) unsigned Pbuf[8][16 * PSTR];

    // XCD-aware swizzle: 2048 blocks, 8 XCDs -> contiguous 256-block chunk/XCD
    const unsigned bid = (blockIdx.x & 7) * 256 + (blockIdx.x >> 3);
    const int cid = bid & 31;          // chunk id
    const int h   = (bid >> 5) & 15;   // head
    const int b   = bid >> 9;          // batch
    const int q0  = cid * CHUNKQ;
    const int hi  = q0 + CHUNKQ;
    const int kstart = (hi - 320 > 0) ? (hi - 320) : 0;
    const int KT  = hi - kstart;       // 64..320, multiple of 64

    const int tid = threadIdx.x;
    const int e4  = (tid & 7) * 4;     // K-staging dim 0,4,..,28
    const int r0  = tid >> 3;          // K-staging key row 0..63
    const int d2  = (tid & 15) * 2;    // V-staging dim pair 0,2,..,30
    const int kp  = tid >> 4;          // V-staging key-pair 0..31

    // ---- staging loads: ALL issued first, unconditional (always in-bounds:
    //      kstart + row <= kstart+319 <= 2047; extra cols never read) ----
    float4 fk[5];
    float2 va[5], vb[5];
    #pragma unroll
    for (int it = 0; it < 5; ++it) {
        const size_t kbase = (size_t)(b * SEQ + kstart + r0 + it * 64) * EMB + h * DH + e4;
        fk[it] = *(const float4*)(k + kbase);
        const size_t vbase = (size_t)(b * SEQ + kstart + 64 * it + 2 * kp) * EMB + h * DH + d2;
        va[it] = *(const float2*)(v + vbase);          // key 64it+2kp, dims d2,d2+1
        vb[it] = *(const float2*)(v + vbase + EMB);    // key 64it+2kp+1
    }

    const int w   = tid >> 6;          // wave 0..7
    const int wq  = w & 3;             // query block: queries [16wq,16wq+16)
    const int ph  = w >> 2;            // key-tile parity phase
    const int l   = tid & 63;
    const int l16 = l & 15;
    const int kg  = l >> 4;            // 0..3
    const int k0  = kg * 8;            // dim slice for frags

    // ---- Q B-frag direct from global (overlaps the staging-load latency) ----
    const float* qrow = q + ((size_t)(b * SEQ + q0 + 16 * wq + l16) * EMB + h * DH + k0);
    const float4 qa = *(const float4*)qrow;
    const float4 qc = *(const float4*)(qrow + 4);
    union { short8 s; unsigned u[4]; } qb;
    qb.u[0] = cvt_pk_bf16(qa.x, qa.y);
    qb.u[1] = cvt_pk_bf16(qa.z, qa.w);
    qb.u[2] = cvt_pk_bf16(qc.x, qc.y);
    qb.u[3] = cvt_pk_bf16(qc.z, qc.w);

    // ---- staging converts + LDS writes (unconditional) ----
    #pragma unroll
    for (int it = 0; it < 5; ++it) {
        uint2 kw;
        kw.x = cvt_pk_bf16(fk[it].x, fk[it].y);
        kw.y = cvt_pk_bf16(fk[it].z, fk[it].w);
        *(uint2*)(Ks + (r0 + it * 64) * KSTR + e4) = kw;   // 8B aligned
        *(unsigned*)(Vt + (d2 + 0) * VSTR + 64 * it + 2 * kp) = cvt_pk_bf16(va[it].x, vb[it].x);
        *(unsigned*)(Vt + (d2 + 1) * VSTR + 64 * it + 2 * kp) = cvt_pk_bf16(va[it].y, vb[it].y);
    }
    __syncthreads();

    const float scale = 0.17677669529663687f;  // 1/sqrt(32)
    const int   iq    = q0 + 16 * wq + l16;    // this lane's query (key-major domain)
    const int   lowk  = iq - (WIN - 1);        // allowed keys: [lowk, hi)
    unsigned* pw = &Pbuf[w][l16 * PSTR];

    const f32x4 zero = {0.f, 0.f, 0.f, 0.f};
    f32x4 o0 = zero, o1 = zero;
    float srow = 0.f;

    #pragma unroll
    for (int i = 0; i < 5; ++i) {
        const int t = 2 * i + ph;      // phase 0: even tiles, phase 1: odd
        if (t * 32 < KT) {
            // QK^T (swapped): A = K rows, B = Q. D[key=4kg+r][q=l16]
            const short8 ka = *(const short8*)(Ks + (32 * t + l16) * KSTR + k0);
            const short8 kb = *(const short8*)(Ks + (32 * t + 16 + l16) * KSTR + k0);
            f32x4 s_lo = __builtin_amdgcn_mfma_f32_16x16x32_bf16(ka, qb.s, zero, 0, 0, 0);
            f32x4 s_hi = __builtin_amdgcn_mfma_f32_16x16x32_bf16(kb, qb.s, zero, 0, 0, 0);

            // mask + exp (no max-sub: scores bounded, fp32-safe); sum in-lane
            const int kk = kstart + 32 * t + 4 * kg;
            float p[8];
            #pragma unroll
            for (int r = 0; r < 4; ++r) {
                p[r]     = (kk + r      >= lowk) ? __expf(s_lo[r] * scale) : 0.f;
                p[r + 4] = (kk + r + 16 >= lowk) ? __expf(s_hi[r] * scale) : 0.f;
            }
            srow += ((p[0] + p[1]) + (p[2] + p[3])) + ((p[4] + p[5]) + (p[6] + p[7]));

            // pack & transit through wave-private Pbuf to A-frag layout
            uint2 wlo, whi;
            wlo.x = cvt_pk_bf16(p[0], p[1]);  wlo.y = cvt_pk_bf16(p[2], p[3]);
            whi.x = cvt_pk_bf16(p[4], p[5]);  whi.y = cvt_pk_bf16(p[6], p[7]);
            *(uint2*)(pw + 2 * kg)     = wlo;   // keys 4kg..4kg+3
            *(uint2*)(pw + 8 + 2 * kg) = whi;   // keys 16+4kg..+3
            const short8 pa = *(const short8*)(pw + 4 * kg);  // P[q=l16][keys 8kg..8kg+7]

            // PV: B = Vt rows (dims), accumulate
            const short8 bv0 = *(const short8*)(Vt + l16 * VSTR + 32 * t + k0);
            const short8 bv1 = *(const short8*)(Vt + (16 + l16) * VSTR + 32 * t + k0);
            o0 = __builtin_amdgcn_mfma_f32_16x16x32_bf16(pa, bv0, o0, 0, 0, 0);
            o1 = __builtin_amdgcn_mfma_f32_16x16x32_bf16(pa, bv1, o1, 0, 0, 0);
        }
    }

    // ---- combine phases: Ks is dead now; overlay partial buffer on it ----
    float* Obuf = (float*)Ks;          // [4 query-blocks][64 lanes][9 floats]
    __syncthreads();                   // all Ks reads done before overlay
    if (ph == 1) {
        float* ob = Obuf + ((size_t)wq * 64 + l) * 9;
        ob[0] = o0[0]; ob[1] = o0[1]; ob[2] = o0[2]; ob[3] = o0[3];
        ob[4] = o1[0]; ob[5] = o1[1]; ob[6] = o1[2]; ob[7] = o1[3];
        ob[8] = srow;
    }
    __syncthreads();
    if (ph == 0) {
        const float* ob = Obuf + ((size_t)wq * 64 + l) * 9;
        o0[0] += ob[0]; o0[1] += ob[1]; o0[2] += ob[2]; o0[3] += ob[3];
        o1[0] += ob[4]; o1[1] += ob[5]; o1[2] += ob[6]; o1[3] += ob[7];
        srow  += ob[8];

        // reduce row-sum (keys partitioned over kg/halves), normalize, write
        srow += __shfl_xor(srow, 16);
        srow += __shfl_xor(srow, 32);
        #pragma unroll
        for (int r = 0; r < 4; ++r) {
            const float sq  = __shfl(srow, 4 * kg + r);
            const float inv = 1.0f / sq;
            float* dst = out + (size_t)(b * SEQ + q0 + 16 * wq + 4 * kg + r) * EMB + h * DH;
            dst[l16]      = o0[r] * inv;
            dst[16 + l16] = o1[r] * inv;
        }
    }
}

extern "C" void kernel_launch(void* const* d_in, const int* in_sizes, int n_in,
                              void* d_out, int out_size, void* d_ws, size_t ws_size,
                              hipStream_t stream) {
    const float* q = (const float*)d_in[0];
    const float* k = (const float*)d_in[1];
    const float* v = (const float*)d_in[2];
    float* out = (float*)d_out;
    const int grid = NB * NH * (SEQ / CHUNKQ);   // 2048 blocks, 1 chunk each
    attn_chunk_kernel<<<grid, 512, 0, stream>>>(q, k, v, out);
}

// Round 12
// 27.006 us; speedup vs baseline: 2.0107x; 1.0245x over previous
//
#include <hip/hip_runtime.h>
#include <hip/hip_bf16.h>

#define NB 4
#define NH 16
#define SEQ 2048
#define EMB 512
#define DH 32
#define CHUNKQ 64
#define WIN 256

typedef __attribute__((ext_vector_type(8))) short short8;
typedef __attribute__((ext_vector_type(4))) float f32x4;

// packed f32x2 -> bf16x2 (RNE); HW-validated rounds 3/6/8
__device__ __forceinline__ unsigned cvt_pk_bf16(float lo, float hi) {
    unsigned r;
    asm("v_cvt_pk_bf16_f32 %0, %1, %2" : "=v"(r) : "v"(lo), "v"(hi));
    return r;
}

// === r8 (green, 26.4us) + ONE delta: 2 independent streams per wave ===
// Each iteration i processes tile pair (2i, 2i+1) with fully disjoint state:
// separate scores/exp regs, separate Pbuf half-rows (A: words 0-15, B: 16-31),
// separate accumulators (merged at the end). While stream A stalls on its
// Pbuf write->read round-trip (DS ops complete in-order per wave), stream B's
// Ks reads / QK MFMA / exp issue -> 2x issuable work per wave at the stall
// points. KT % 64 == 0 -> one guard per pair.
//
// KSTR 40->36 so LDS stays 3 blocks/CU: Ks [320][36] (23040 B) + Vt [32][328]
// (20992 B) + Pbuf 4 x [16][36] u32 (9216 B) = 53248 B; 3x53248 < 160 KiB.
// Bank math re-derived for KSTR=36: b128 reads 8 sweeps (min), uint2 writes
// 4 sweeps (min) -- conflict-free. All other mechanics verbatim r8.

__global__ __launch_bounds__(256, 3)
void attn_chunk_kernel(const float* __restrict__ q, const float* __restrict__ k,
                       const float* __restrict__ v, float* __restrict__ out)
{
    constexpr int KSTR = 36;    // Ks row stride (bf16)
    constexpr int VSTR = 328;   // Vt row stride (bf16)
    constexpr int PSTR = 36;    // Pbuf row stride (u32): A words 0-15, B 16-31
    __shared__ __align__(16) ushort Ks[320 * KSTR];
    __shared__ __align__(16) ushort Vt[32 * VSTR];
    __shared__ __align__(16) unsigned Pbuf[4][16 * PSTR];

    // XCD-aware swizzle: 2048 blocks, 8 XCDs -> contiguous 256-block chunk/XCD
    const unsigned bid = (blockIdx.x & 7) * 256 + (blockIdx.x >> 3);
    const int cid = bid & 31;          // chunk id
    const int h   = (bid >> 5) & 15;   // head
    const int b   = bid >> 9;          // batch
    const int q0  = cid * CHUNKQ;
    const int hi  = q0 + CHUNKQ;
    const int kstart = (hi - 320 > 0) ? (hi - 320) : 0;
    const int KT  = hi - kstart;       // 64..320, multiple of 64

    const int tid = threadIdx.x;
    const int e4  = (tid & 7) * 4;     // K-staging dim 0,4,..,28
    const int r0  = tid >> 3;          // K-staging key row 0..31
    const int d2  = (tid & 15) * 2;    // V-staging dim pair 0,2,..,30
    const int kp  = tid >> 4;          // V-staging key-pair 0..15

    // ---- staging loads: ALL issued first, unconditional (always in-bounds:
    //      kstart + row <= hi-1 <= 2047; extra cols written but never read) ----
    float4 fk[10];
    float2 va[10], vb[10];
    #pragma unroll
    for (int it = 0; it < 10; ++it) {
        const size_t kbase = (size_t)(b * SEQ + kstart + r0 + it * 32) * EMB + h * DH + e4;
        fk[it] = *(const float4*)(k + kbase);
        const size_t vbase = (size_t)(b * SEQ + kstart + 32 * it + 2 * kp) * EMB + h * DH + d2;
        va[it] = *(const float2*)(v + vbase);          // key 32it+2kp, dims d2,d2+1
        vb[it] = *(const float2*)(v + vbase + EMB);    // key 32it+2kp+1
    }

    const int w   = tid >> 6;          // wave 0..3 owns queries [16w, 16w+16)
    const int l   = tid & 63;
    const int l16 = l & 15;
    const int kg  = l >> 4;            // 0..3
    const int k0  = kg * 8;            // dim slice for frags

    // ---- Q B-frag direct from global (overlaps the staging-load latency) ----
    const float* qrow = q + ((size_t)(b * SEQ + q0 + 16 * w + l16) * EMB + h * DH + k0);
    const float4 qa = *(const float4*)qrow;
    const float4 qc = *(const float4*)(qrow + 4);
    union { short8 s; unsigned u[4]; } qb;
    qb.u[0] = cvt_pk_bf16(qa.x, qa.y);
    qb.u[1] = cvt_pk_bf16(qa.z, qa.w);
    qb.u[2] = cvt_pk_bf16(qc.x, qc.y);
    qb.u[3] = cvt_pk_bf16(qc.z, qc.w);

    // ---- staging converts + LDS writes (unconditional) ----
    #pragma unroll
    for (int it = 0; it < 10; ++it) {
        uint2 kw;
        kw.x = cvt_pk_bf16(fk[it].x, fk[it].y);
        kw.y = cvt_pk_bf16(fk[it].z, fk[it].w);
        *(uint2*)(Ks + (r0 + it * 32) * KSTR + e4) = kw;   // 8B aligned
        *(unsigned*)(Vt + (d2 + 0) * VSTR + 32 * it + 2 * kp) = cvt_pk_bf16(va[it].x, vb[it].x);
        *(unsigned*)(Vt + (d2 + 1) * VSTR + 32 * it + 2 * kp) = cvt_pk_bf16(va[it].y, vb[it].y);
    }
    __syncthreads();   // the only barrier

    const float scale = 0.17677669529663687f;  // 1/sqrt(32)
    const int   iq    = q0 + 16 * w + l16;     // this lane's query (key-major domain)
    const int   lowk  = iq - (WIN - 1);        // allowed keys: [lowk, hi)
    unsigned* pwA = &Pbuf[w][l16 * PSTR];      // stream A: words 0..15
    unsigned* pwB = pwA + 16;                  // stream B: words 16..31

    const f32x4 zero = {0.f, 0.f, 0.f, 0.f};
    f32x4 o0A = zero, o1A = zero, o0B = zero, o1B = zero;
    float srowA = 0.f, srowB = 0.f;

    #pragma unroll
    for (int i = 0; i < 5; ++i) {
        if (i * 64 < KT) {      // KT % 64 == 0 -> tiles 2i and 2i+1 live together
            const int tA = 2 * i, tB = 2 * i + 1;

            // Ks reads + QK^T, both streams (independent chains)
            const short8 kaA = *(const short8*)(Ks + (32 * tA + l16) * KSTR + k0);
            const short8 kbA = *(const short8*)(Ks + (32 * tA + 16 + l16) * KSTR + k0);
            const short8 kaB = *(const short8*)(Ks + (32 * tB + l16) * KSTR + k0);
            const short8 kbB = *(const short8*)(Ks + (32 * tB + 16 + l16) * KSTR + k0);
            f32x4 sAlo = __builtin_amdgcn_mfma_f32_16x16x32_bf16(kaA, qb.s, zero, 0, 0, 0);
            f32x4 sAhi = __builtin_amdgcn_mfma_f32_16x16x32_bf16(kbA, qb.s, zero, 0, 0, 0);
            f32x4 sBlo = __builtin_amdgcn_mfma_f32_16x16x32_bf16(kaB, qb.s, zero, 0, 0, 0);
            f32x4 sBhi = __builtin_amdgcn_mfma_f32_16x16x32_bf16(kbB, qb.s, zero, 0, 0, 0);

            // mask + exp (no max-sub: scores bounded, fp32-safe); sums in-lane
            const int kkA = kstart + 32 * tA + 4 * kg;
            const int kkB = kkA + 32;
            float pA[8], pB[8];
            #pragma unroll
            for (int r = 0; r < 4; ++r) {
                pA[r]     = (kkA + r      >= lowk) ? __expf(sAlo[r] * scale) : 0.f;
                pA[r + 4] = (kkA + r + 16 >= lowk) ? __expf(sAhi[r] * scale) : 0.f;
                pB[r]     = (kkB + r      >= lowk) ? __expf(sBlo[r] * scale) : 0.f;
                pB[r + 4] = (kkB + r + 16 >= lowk) ? __expf(sBhi[r] * scale) : 0.f;
            }
            srowA += ((pA[0] + pA[1]) + (pA[2] + pA[3])) + ((pA[4] + pA[5]) + (pA[6] + pA[7]));
            srowB += ((pB[0] + pB[1]) + (pB[2] + pB[3])) + ((pB[4] + pB[5]) + (pB[6] + pB[7]));

            // pack & transit through disjoint Pbuf half-rows
            uint2 wloA, whiA, wloB, whiB;
            wloA.x = cvt_pk_bf16(pA[0], pA[1]);  wloA.y = cvt_pk_bf16(pA[2], pA[3]);
            whiA.x = cvt_pk_bf16(pA[4], pA[5]);  whiA.y = cvt_pk_bf16(pA[6], pA[7]);
            wloB.x = cvt_pk_bf16(pB[0], pB[1]);  wloB.y = cvt_pk_bf16(pB[2], pB[3]);
            whiB.x = cvt_pk_bf16(pB[4], pB[5]);  whiB.y = cvt_pk_bf16(pB[6], pB[7]);
            *(uint2*)(pwA + 2 * kg)     = wloA;
            *(uint2*)(pwA + 8 + 2 * kg) = whiA;
            *(uint2*)(pwB + 2 * kg)     = wloB;
            *(uint2*)(pwB + 8 + 2 * kg) = whiB;
            const short8 paA = *(const short8*)(pwA + 4 * kg);
            const short8 paB = *(const short8*)(pwB + 4 * kg);

            // PV, both streams
            const short8 bv0A = *(const short8*)(Vt + l16 * VSTR + 32 * tA + k0);
            const short8 bv1A = *(const short8*)(Vt + (16 + l16) * VSTR + 32 * tA + k0);
            const short8 bv0B = *(const short8*)(Vt + l16 * VSTR + 32 * tB + k0);
            const short8 bv1B = *(const short8*)(Vt + (16 + l16) * VSTR + 32 * tB + k0);
            o0A = __builtin_amdgcn_mfma_f32_16x16x32_bf16(paA, bv0A, o0A, 0, 0, 0);
            o1A = __builtin_amdgcn_mfma_f32_16x16x32_bf16(paA, bv1A, o1A, 0, 0, 0);
            o0B = __builtin_amdgcn_mfma_f32_16x16x32_bf16(paB, bv0B, o0B, 0, 0, 0);
            o1B = __builtin_amdgcn_mfma_f32_16x16x32_bf16(paB, bv1B, o1B, 0, 0, 0);
        }
    }

    // ---- merge streams, reduce row-sum, normalize, write ----
    f32x4 o0, o1;
    #pragma unroll
    for (int r = 0; r < 4; ++r) { o0[r] = o0A[r] + o0B[r]; o1[r] = o1A[r] + o1B[r]; }
    float srow = srowA + srowB;
    srow += __shfl_xor(srow, 16);
    srow += __shfl_xor(srow, 32);   // srow(q=l16) valid in all kg groups
    #pragma unroll
    for (int r = 0; r < 4; ++r) {
        const float sq  = __shfl(srow, 4 * kg + r);     // srow for query 4kg+r
        const float inv = 1.0f / sq;
        float* dst = out + (size_t)(b * SEQ + q0 + 16 * w + 4 * kg + r) * EMB + h * DH;
        dst[l16]      = o0[r] * inv;
        dst[16 + l16] = o1[r] * inv;
    }
}

extern "C" void kernel_launch(void* const* d_in, const int* in_sizes, int n_in,
                              void* d_out, int out_size, void* d_ws, size_t ws_size,
                              hipStream_t stream) {
    const float* q = (const float*)d_in[0];
    const float* k = (const float*)d_in[1];
    const float* v = (const float*)d_in[2];
    float* out = (float*)d_out;
    const int grid = NB * NH * (SEQ / CHUNKQ);   // 2048 blocks
    attn_chunk_kernel<<<grid, 256, 0, stream>>>(q, k, v, out);
}

// Round 13
// 26.764 us; speedup vs baseline: 2.0289x; 1.0091x over previous
//
#include <hip/hip_runtime.h>
#include <hip/hip_bf16.h>

#define NB 4
#define NH 16
#define SEQ 2048
#define EMB 512
#define DH 32
#define CHUNKQ 64
#define WIN 256

typedef __attribute__((ext_vector_type(8))) short short8;
typedef __attribute__((ext_vector_type(4))) float f32x4;

// packed f32x2 -> bf16x2 (RNE); HW-validated rounds 3/6/8
__device__ __forceinline__ unsigned cvt_pk_bf16(float lo, float hi) {
    unsigned r;
    asm("v_cvt_pk_bf16_f32 %0, %1, %2" : "=v"(r) : "v"(lo), "v"(hi));
    return r;
}

// === r8 (green, 26.4us) + ONE delta: sched_barrier(0) load fence ===
// r8's VGPR_Count=56 proves the compiler SANK the 20 staging loads to their
// uses (keeping them in flight needs >=60 landing VGPRs) -> staging ran as
// ~5 serialized load->cvt->write batches (~500cy each). The fence forbids
// any instruction crossing between the load block and the convert/write
// block, forcing all loads issued first -> one overlapped memory latency.
// Everything else byte-identical to r8.
//
// LDS: Ks [320][40] (25600) + Vt [32][328] (20992) + Pbuf 4x[16][20] u32
// (5120) = 51712 B -> 3 blocks/CU.

__global__ __launch_bounds__(256, 3)
void attn_chunk_kernel(const float* __restrict__ q, const float* __restrict__ k,
                       const float* __restrict__ v, float* __restrict__ out)
{
    constexpr int KSTR = 40;    // Ks row stride (bf16)
    constexpr int VSTR = 328;   // Vt row stride (bf16)
    constexpr int PSTR = 20;    // Pbuf row stride (u32)
    __shared__ __align__(16) ushort Ks[320 * KSTR];
    __shared__ __align__(16) ushort Vt[32 * VSTR];
    __shared__ __align__(16) unsigned Pbuf[4][16 * PSTR];

    // XCD-aware swizzle: 2048 blocks, 8 XCDs -> contiguous 256-block chunk/XCD
    const unsigned bid = (blockIdx.x & 7) * 256 + (blockIdx.x >> 3);
    const int cid = bid & 31;          // chunk id
    const int h   = (bid >> 5) & 15;   // head
    const int b   = bid >> 9;          // batch
    const int q0  = cid * CHUNKQ;
    const int hi  = q0 + CHUNKQ;
    const int kstart = (hi - 320 > 0) ? (hi - 320) : 0;
    const int KT  = hi - kstart;       // 64..320, multiple of 64

    const int tid = threadIdx.x;
    const int e4  = (tid & 7) * 4;     // K-staging dim 0,4,..,28
    const int r0  = tid >> 3;          // K-staging key row 0..31
    const int d2  = (tid & 15) * 2;    // V-staging dim pair 0,2,..,30
    const int kp  = tid >> 4;          // V-staging key-pair 0..15

    const int w   = tid >> 6;          // wave 0..3 owns queries [16w, 16w+16)
    const int l   = tid & 63;
    const int l16 = l & 15;
    const int kg  = l >> 4;            // 0..3
    const int k0  = kg * 8;            // dim slice for frags

    // ---- ALL global loads issued first, unconditional (always in-bounds:
    //      kstart + row <= hi-1 <= 2047; extra cols written but never read) ----
    float4 fk[10];
    float2 va[10], vb[10];
    #pragma unroll
    for (int it = 0; it < 10; ++it) {
        const size_t kbase = (size_t)(b * SEQ + kstart + r0 + it * 32) * EMB + h * DH + e4;
        fk[it] = *(const float4*)(k + kbase);
        const size_t vbase = (size_t)(b * SEQ + kstart + 32 * it + 2 * kp) * EMB + h * DH + d2;
        va[it] = *(const float2*)(v + vbase);          // key 32it+2kp, dims d2,d2+1
        vb[it] = *(const float2*)(v + vbase + EMB);    // key 32it+2kp+1
    }
    const float* qrow = q + ((size_t)(b * SEQ + q0 + 16 * w + l16) * EMB + h * DH + k0);
    const float4 qa = *(const float4*)qrow;
    const float4 qc = *(const float4*)(qrow + 4);

    // ---- fence: nothing crosses; all 21 loads stay issued above ----
    __builtin_amdgcn_sched_barrier(0);

    // ---- Q B-frag convert ----
    union { short8 s; unsigned u[4]; } qb;
    qb.u[0] = cvt_pk_bf16(qa.x, qa.y);
    qb.u[1] = cvt_pk_bf16(qa.z, qa.w);
    qb.u[2] = cvt_pk_bf16(qc.x, qc.y);
    qb.u[3] = cvt_pk_bf16(qc.z, qc.w);

    // ---- staging converts + LDS writes (unconditional) ----
    #pragma unroll
    for (int it = 0; it < 10; ++it) {
        uint2 kw;
        kw.x = cvt_pk_bf16(fk[it].x, fk[it].y);
        kw.y = cvt_pk_bf16(fk[it].z, fk[it].w);
        *(uint2*)(Ks + (r0 + it * 32) * KSTR + e4) = kw;   // 8B aligned
        *(unsigned*)(Vt + (d2 + 0) * VSTR + 32 * it + 2 * kp) = cvt_pk_bf16(va[it].x, vb[it].x);
        *(unsigned*)(Vt + (d2 + 1) * VSTR + 32 * it + 2 * kp) = cvt_pk_bf16(va[it].y, vb[it].y);
    }
    __syncthreads();   // the only barrier

    const float scale = 0.17677669529663687f;  // 1/sqrt(32)
    const int   iq    = q0 + 16 * w + l16;     // this lane's query (key-major domain)
    const int   lowk  = iq - (WIN - 1);        // allowed keys: [lowk, hi)
    unsigned* pw = &Pbuf[w][l16 * PSTR];

    const f32x4 zero = {0.f, 0.f, 0.f, 0.f};
    f32x4 o0 = zero, o1 = zero;
    float srow = 0.f;

    #pragma unroll
    for (int t = 0; t < 10; ++t) {
        if (t * 32 < KT) {
            // QK^T (swapped): A = K rows, B = Q. D[key=4kg+r][q=l16]
            const short8 ka = *(const short8*)(Ks + (32 * t + l16) * KSTR + k0);
            const short8 kb = *(const short8*)(Ks + (32 * t + 16 + l16) * KSTR + k0);
            f32x4 s_lo = __builtin_amdgcn_mfma_f32_16x16x32_bf16(ka, qb.s, zero, 0, 0, 0);
            f32x4 s_hi = __builtin_amdgcn_mfma_f32_16x16x32_bf16(kb, qb.s, zero, 0, 0, 0);

            // mask + exp (no max-sub: scores bounded, fp32-safe); sum in-lane
            const int kk = kstart + 32 * t + 4 * kg;
            float p[8];
            #pragma unroll
            for (int r = 0; r < 4; ++r) {
                p[r]     = (kk + r      >= lowk) ? __expf(s_lo[r] * scale) : 0.f;
                p[r + 4] = (kk + r + 16 >= lowk) ? __expf(s_hi[r] * scale) : 0.f;
            }
            srow += ((p[0] + p[1]) + (p[2] + p[3])) + ((p[4] + p[5]) + (p[6] + p[7]));

            // pack & transit through wave-private Pbuf to A-frag layout
            uint2 wlo, whi;
            wlo.x = cvt_pk_bf16(p[0], p[1]);  wlo.y = cvt_pk_bf16(p[2], p[3]);
            whi.x = cvt_pk_bf16(p[4], p[5]);  whi.y = cvt_pk_bf16(p[6], p[7]);
            *(uint2*)(pw + 2 * kg)     = wlo;   // keys 4kg..4kg+3
            *(uint2*)(pw + 8 + 2 * kg) = whi;   // keys 16+4kg..+3
            const short8 pa = *(const short8*)(pw + 4 * kg);  // P[q=l16][keys 8kg..8kg+7]

            // PV: B = Vt rows (dims), accumulate
            const short8 bv0 = *(const short8*)(Vt + l16 * VSTR + 32 * t + k0);
            const short8 bv1 = *(const short8*)(Vt + (16 + l16) * VSTR + 32 * t + k0);
            o0 = __builtin_amdgcn_mfma_f32_16x16x32_bf16(pa, bv0, o0, 0, 0, 0);
            o1 = __builtin_amdgcn_mfma_f32_16x16x32_bf16(pa, bv1, o1, 0, 0, 0);
        }
    }

    // ---- epilogue: reduce row-sum (keys partitioned over kg/halves), write ----
    srow += __shfl_xor(srow, 16);
    srow += __shfl_xor(srow, 32);   // srow(q=l16) valid in all kg groups
    #pragma unroll
    for (int r = 0; r < 4; ++r) {
        const float sq  = __shfl(srow, 4 * kg + r);     // srow for query 4kg+r
        const float inv = 1.0f / sq;
        float* dst = out + (size_t)(b * SEQ + q0 + 16 * w + 4 * kg + r) * EMB + h * DH;
        dst[l16]      = o0[r] * inv;
        dst[16 + l16] = o1[r] * inv;
    }
}

extern "C" void kernel_launch(void* const* d_in, const int* in_sizes, int n_in,
                              void* d_out, int out_size, void* d_ws, size_t ws_size,
                              hipStream_t stream) {
    const float* q = (const float*)d_in[0];
    const float* k = (const float*)d_in[1];
    const float* v = (const float*)d_in[2];
    float* out = (float*)d_out;
    const int grid = NB * NH * (SEQ / CHUNKQ);   // 2048 blocks
    attn_chunk_kernel<<<grid, 256, 0, stream>>>(q, k, v, out);
}

// Round 14
// 26.687 us; speedup vs baseline: 2.0348x; 1.0029x over previous
//
#include <hip/hip_runtime.h>
#include <hip/hip_bf16.h>

#define NB 4
#define NH 16
#define SEQ 2048
#define EMB 512
#define DH 32
#define CHUNKQ 64
#define WIN 256

typedef __attribute__((ext_vector_type(8))) short short8;
typedef __attribute__((ext_vector_type(4))) float f32x4;

// packed f32x2 -> bf16x2 (RNE); HW-validated rounds 3/6/8
__device__ __forceinline__ unsigned cvt_pk_bf16(float lo, float hi) {
    unsigned r;
    asm("v_cvt_pk_bf16_f32 %0, %1, %2" : "=v"(r) : "v"(lo), "v"(hi));
    return r;
}

// === r8 (green, 26.4us) + ONE delta: s_setprio(1) across the t-loop (T5) ===
// 3 desynced blocks/CU put loop-phase waves (latency-critical MFMA chain)
// next to staging-phase waves (latency-tolerant VMEM). Raising loop-wave
// priority wins issue arbitration at every contested slot; proven +4-7% on
// attention with phase-diverse waves (m191), null only in lockstep (m190).
// Everything else byte-identical to r8.
//
// LDS: Ks [320][40] (25600) + Vt [32][328] (20992) + Pbuf 4x[16][20] u32
// (5120) = 51712 B -> 3 blocks/CU.

__global__ __launch_bounds__(256, 3)
void attn_chunk_kernel(const float* __restrict__ q, const float* __restrict__ k,
                       const float* __restrict__ v, float* __restrict__ out)
{
    constexpr int KSTR = 40;    // Ks row stride (bf16)
    constexpr int VSTR = 328;   // Vt row stride (bf16)
    constexpr int PSTR = 20;    // Pbuf row stride (u32)
    __shared__ __align__(16) ushort Ks[320 * KSTR];
    __shared__ __align__(16) ushort Vt[32 * VSTR];
    __shared__ __align__(16) unsigned Pbuf[4][16 * PSTR];

    // XCD-aware swizzle: 2048 blocks, 8 XCDs -> contiguous 256-block chunk/XCD
    const unsigned bid = (blockIdx.x & 7) * 256 + (blockIdx.x >> 3);
    const int cid = bid & 31;          // chunk id
    const int h   = (bid >> 5) & 15;   // head
    const int b   = bid >> 9;          // batch
    const int q0  = cid * CHUNKQ;
    const int hi  = q0 + CHUNKQ;
    const int kstart = (hi - 320 > 0) ? (hi - 320) : 0;
    const int KT  = hi - kstart;       // 64..320, multiple of 64

    const int tid = threadIdx.x;
    const int e4  = (tid & 7) * 4;     // K-staging dim 0,4,..,28
    const int r0  = tid >> 3;          // K-staging key row 0..31
    const int d2  = (tid & 15) * 2;    // V-staging dim pair 0,2,..,30
    const int kp  = tid >> 4;          // V-staging key-pair 0..15

    // ---- staging loads: ALL issued first, unconditional (always in-bounds:
    //      kstart + row <= hi-1 <= 2047; extra cols written but never read) ----
    float4 fk[10];
    float2 va[10], vb[10];
    #pragma unroll
    for (int it = 0; it < 10; ++it) {
        const size_t kbase = (size_t)(b * SEQ + kstart + r0 + it * 32) * EMB + h * DH + e4;
        fk[it] = *(const float4*)(k + kbase);
        const size_t vbase = (size_t)(b * SEQ + kstart + 32 * it + 2 * kp) * EMB + h * DH + d2;
        va[it] = *(const float2*)(v + vbase);          // key 32it+2kp, dims d2,d2+1
        vb[it] = *(const float2*)(v + vbase + EMB);    // key 32it+2kp+1
    }

    const int w   = tid >> 6;          // wave 0..3 owns queries [16w, 16w+16)
    const int l   = tid & 63;
    const int l16 = l & 15;
    const int kg  = l >> 4;            // 0..3
    const int k0  = kg * 8;            // dim slice for frags

    // ---- Q B-frag direct from global (overlaps the staging-load latency) ----
    const float* qrow = q + ((size_t)(b * SEQ + q0 + 16 * w + l16) * EMB + h * DH + k0);
    const float4 qa = *(const float4*)qrow;
    const float4 qc = *(const float4*)(qrow + 4);
    union { short8 s; unsigned u[4]; } qb;
    qb.u[0] = cvt_pk_bf16(qa.x, qa.y);
    qb.u[1] = cvt_pk_bf16(qa.z, qa.w);
    qb.u[2] = cvt_pk_bf16(qc.x, qc.y);
    qb.u[3] = cvt_pk_bf16(qc.z, qc.w);

    // ---- staging converts + LDS writes (unconditional) ----
    #pragma unroll
    for (int it = 0; it < 10; ++it) {
        uint2 kw;
        kw.x = cvt_pk_bf16(fk[it].x, fk[it].y);
        kw.y = cvt_pk_bf16(fk[it].z, fk[it].w);
        *(uint2*)(Ks + (r0 + it * 32) * KSTR + e4) = kw;   // 8B aligned
        *(unsigned*)(Vt + (d2 + 0) * VSTR + 32 * it + 2 * kp) = cvt_pk_bf16(va[it].x, vb[it].x);
        *(unsigned*)(Vt + (d2 + 1) * VSTR + 32 * it + 2 * kp) = cvt_pk_bf16(va[it].y, vb[it].y);
    }
    __syncthreads();   // the only barrier

    const float scale = 0.17677669529663687f;  // 1/sqrt(32)
    const int   iq    = q0 + 16 * w + l16;     // this lane's query (key-major domain)
    const int   lowk  = iq - (WIN - 1);        // allowed keys: [lowk, hi)
    unsigned* pw = &Pbuf[w][l16 * PSTR];

    const f32x4 zero = {0.f, 0.f, 0.f, 0.f};
    f32x4 o0 = zero, o1 = zero;
    float srow = 0.f;

    __builtin_amdgcn_s_setprio(1);   // loop waves win arbitration vs staging waves
    #pragma unroll
    for (int t = 0; t < 10; ++t) {
        if (t * 32 < KT) {
            // QK^T (swapped): A = K rows, B = Q. D[key=4kg+r][q=l16]
            const short8 ka = *(const short8*)(Ks + (32 * t + l16) * KSTR + k0);
            const short8 kb = *(const short8*)(Ks + (32 * t + 16 + l16) * KSTR + k0);
            f32x4 s_lo = __builtin_amdgcn_mfma_f32_16x16x32_bf16(ka, qb.s, zero, 0, 0, 0);
            f32x4 s_hi = __builtin_amdgcn_mfma_f32_16x16x32_bf16(kb, qb.s, zero, 0, 0, 0);

            // mask + exp (no max-sub: scores bounded, fp32-safe); sum in-lane
            const int kk = kstart + 32 * t + 4 * kg;
            float p[8];
            #pragma unroll
            for (int r = 0; r < 4; ++r) {
                p[r]     = (kk + r      >= lowk) ? __expf(s_lo[r] * scale) : 0.f;
                p[r + 4] = (kk + r + 16 >= lowk) ? __expf(s_hi[r] * scale) : 0.f;
            }
            srow += ((p[0] + p[1]) + (p[2] + p[3])) + ((p[4] + p[5]) + (p[6] + p[7]));

            // pack & transit through wave-private Pbuf to A-frag layout
            uint2 wlo, whi;
            wlo.x = cvt_pk_bf16(p[0], p[1]);  wlo.y = cvt_pk_bf16(p[2], p[3]);
            whi.x = cvt_pk_bf16(p[4], p[5]);  whi.y = cvt_pk_bf16(p[6], p[7]);
            *(uint2*)(pw + 2 * kg)     = wlo;   // keys 4kg..4kg+3
            *(uint2*)(pw + 8 + 2 * kg) = whi;   // keys 16+4kg..+3
            const short8 pa = *(const short8*)(pw + 4 * kg);  // P[q=l16][keys 8kg..8kg+7]

            // PV: B = Vt rows (dims), accumulate
            const short8 bv0 = *(const short8*)(Vt + l16 * VSTR + 32 * t + k0);
            const short8 bv1 = *(const short8*)(Vt + (16 + l16) * VSTR + 32 * t + k0);
            o0 = __builtin_amdgcn_mfma_f32_16x16x32_bf16(pa, bv0, o0, 0, 0, 0);
            o1 = __builtin_amdgcn_mfma_f32_16x16x32_bf16(pa, bv1, o1, 0, 0, 0);
        }
    }
    __builtin_amdgcn_s_setprio(0);

    // ---- epilogue: reduce row-sum (keys partitioned over kg/halves), write ----
    srow += __shfl_xor(srow, 16);
    srow += __shfl_xor(srow, 32);   // srow(q=l16) valid in all kg groups
    #pragma unroll
    for (int r = 0; r < 4; ++r) {
        const float sq  = __shfl(srow, 4 * kg + r);     // srow for query 4kg+r
        const float inv = 1.0f / sq;
        float* dst = out + (size_t)(b * SEQ + q0 + 16 * w + 4 * kg + r) * EMB + h * DH;
        dst[l16]      = o0[r] * inv;
        dst[16 + l16] = o1[r] * inv;
    }
}

extern "C" void kernel_launch(void* const* d_in, const int* in_sizes, int n_in,
                              void* d_out, int out_size, void* d_ws, size_t ws_size,
                              hipStream_t stream) {
    const float* q = (const float*)d_in[0];
    const float* k = (const float*)d_in[1];
    const float* v = (const float*)d_in[2];
    float* out = (float*)d_out;
    const int grid = NB * NH * (SEQ / CHUNKQ);   // 2048 blocks
    attn_chunk_kernel<<<grid, 256, 0, stream>>>(q, k, v, out);
}